// Round 3
// baseline (339.938 us; speedup 1.0000x reference)
//
#include <hip/hip_runtime.h>

// YOLOv1 loss: 802816 rows x 30 f32, two tensors, scalar out.
// R9: Five structures (R2-R8: compiler gather / global_load_lds / asm gather
// / coalesced+drain / coalesced+pipelined, 8-18 waves/CU, up to 123 KB/CU in
// flight) all pin at 2.6-2.7 TB/s effective. Little's law (6.3 TB/s needs
// ~9 KB/CU outstanding) rules out latency; VALUBusy 4.6% at ~225 ops/row
// rules out clock throttle. The untested regime: free-running smooth demand
// (no per-tile vmcnt(0)+barrier convoy, 24-32 waves/CU) - the structure the
// 4.9-5.4 TB/s RMSNorm/LayerNorm probes use. This round:
//  - k1: 16-lane groups own one row each; 15 contiguous float2 chunks per
//    group (coalesced 120B stripes), box cols via __shfl transpose, class
//    argmax via lexicographic shfl_xor tree (bit-identical to CLS_STEP
//    scan), per-row results parked in LDS by row index so the final tile
//    reduction replays R8's exact summation order (outputs bitwise equal).
//    No staging LDS, no asm, no drains; 1-pass prefetch; ~55 VGPR target.
//  - bw_probe (after k2): 64 MB pure f32x4 stream, 2048 blocks - known-good
//    reference reader. ~12us => structure was the wall; ~24us => ~2.7 TB/s
//    platform wall and next round declares roofline on that evidence.

#define COLS 30
#define NB   3136              // 802816 rows / 256 rows per tile
#define PB2  1568              // persistent blocks; each does exactly 2 tiles

typedef float f32x4 __attribute__((ext_vector_type(4)));
typedef float f32x2 __attribute__((ext_vector_type(2)));

// ---------------- per-row math on named scalars (bit-exact) ---------------
// Split into PRE (box/IoU/select), CLS scan (K2 only), POST (final r).
#define ROW_PRE                                                              \
    const float C = 1.0f / 7.0f;                                             \
    float conf = b2.x;                    /* T[4], exactly 0.0 or 1.0 */     \
    coord = (conf == 1.0f);                                                  \
    noo = 0.0f;                                                              \
    if (conf == 0.0f) {                                                      \
        float d4_ = a2.x - conf;                                             \
        float d9_ = a4.y - b4.y;                                             \
        noo = d4_ * d4_ + d9_ * d9_;                                         \
    }                                                                        \
    float T0 = b0.x, T1 = b0.y, T2v = b1.x, T3 = b1.y;                       \
    float tb0 = T0 * T0, tb1 = T1 * T1, tb2 = T2v * T2v, tb3 = T3 * T3;      \
    float tax = tb0 * C - tb2, tay = tb1 * C - tb3;                          \
    float tbx = tax * C + tb2, tby = tay * C + tb3;                          \
    float areaT = (tbx - tax) * (tby - tay);                                 \
    float pax0 = a0.x * C - a1.x, pay0 = a0.y * C - a1.y;                    \
    float pbx0 = pax0 * C + a1.x, pby0 = pay0 * C + a1.y;                    \
    float pax1 = a2.y * C - a3.y, pay1 = a3.x * C - a4.x;                    \
    float pbx1 = pax1 * C + a3.y, pby1 = pay1 * C + a4.x;                    \
    float ltx = fmaxf(pax0, tax), lty = fmaxf(pay0, tay);                    \
    float rbx = fminf(pbx0, tbx), rby = fminf(pby0, tby);                    \
    float wx = fmaxf(rbx - ltx, 0.0f), wy = fmaxf(rby - lty, 0.0f);          \
    float inter = wx * wy;                                                   \
    float areaP = (pbx0 - pax0) * (pby0 - pay0);                             \
    float iou0 = inter / (areaP + areaT - inter);                            \
    ltx = fmaxf(pax1, tax); lty = fmaxf(pay1, tay);                          \
    rbx = fminf(pbx1, tbx); rby = fminf(pby1, tby);                          \
    wx = fmaxf(rbx - ltx, 0.0f); wy = fmaxf(rby - lty, 0.0f);                \
    inter = wx * wy;                                                         \
    areaP = (pbx1 - pax1) * (pby1 - pay1);                                   \
    float iou1 = inter / (areaP + areaT - inter);                            \
    int idx = (iou1 > iou0) ? 1 : 0;      /* argmax, first on ties */        \
    float sx = idx ? a2.y : a0.x;                                            \
    float sy = idx ? a3.x : a0.y;                                            \
    float sw = idx ? a3.y : a1.x;                                            \
    float sh = idx ? a4.x : a1.y;

#define ROW_CLS                                                              \
    float best = b5.x, pc = a5.x;         /* class argmax, strict > */       \
    CLS_STEP(b5.y,  a5.y)  CLS_STEP(b6.x,  a6.x)  CLS_STEP(b6.y,  a6.y)      \
    CLS_STEP(b7.x,  a7.x)  CLS_STEP(b7.y,  a7.y)  CLS_STEP(b8.x,  a8.x)      \
    CLS_STEP(b8.y,  a8.y)  CLS_STEP(b9.x,  a9.x)  CLS_STEP(b9.y,  a9.y)      \
    CLS_STEP(b10.x, a10.x) CLS_STEP(b10.y, a10.y) CLS_STEP(b11.x, a11.x)     \
    CLS_STEP(b11.y, a11.y) CLS_STEP(b12.x, a12.x) CLS_STEP(b12.y, a12.y)     \
    CLS_STEP(b13.x, a13.x) CLS_STEP(b13.y, a13.y) CLS_STEP(b14.x, a14.x)     \
    CLS_STEP(b14.y, a14.y)

#define ROW_POST                                                             \
    float d0 = sx - T0, d1 = sy - T1, d2 = sw - T2v, d3 = sh - T3;           \
    float dc = pc - 1.0f;                                                    \
    r = d0 * d0 + d1 * d1 + d2 * d2 + d3 * d3 + 2.0f * dc * dc;

#define ROW_MATH_BODY ROW_PRE ROW_CLS ROW_POST

#define CLS_STEP(tv, pv) { float v_ = (tv); if (v_ > best) { best = v_; pc = (pv); } }

// Plain-C++ row load+compute (used only in K2's 256-row fixup).
__device__ __forceinline__ void row_load_compute(
    const float* __restrict__ gp, const float* __restrict__ gt, long row,
    bool& coord, float& r, float& noo)
{
    const float2* P2 = (const float2*)(gp + row * (long)COLS);
    const float2* T2 = (const float2*)(gt + row * (long)COLS);
    float2 a0 = P2[0],  a1 = P2[1],  a2 = P2[2],  a3 = P2[3],  a4 = P2[4];
    float2 a5 = P2[5],  a6 = P2[6],  a7 = P2[7],  a8 = P2[8],  a9 = P2[9];
    float2 a10 = P2[10], a11 = P2[11], a12 = P2[12], a13 = P2[13], a14 = P2[14];
    float2 b0 = T2[0],  b1 = T2[1],  b2 = T2[2],  b3 = T2[3],  b4 = T2[4];
    float2 b5 = T2[5],  b6 = T2[6],  b7 = T2[7],  b8 = T2[8],  b9 = T2[9];
    float2 b10 = T2[10], b11 = T2[11], b12 = T2[12], b13 = T2[13], b14 = T2[14];
    (void)b3;
    ROW_MATH_BODY
}

// K1: free-running 16-lane-group kernel. Group owns one row per pass;
// 16 passes cover a 256-row tile; each block loops over 2 tiles.
__global__ __launch_bounds__(256, 6) void yolo_k1(const float* __restrict__ gp,
                                                  const float* __restrict__ gt,
                                                  int* __restrict__ cnt,
                                                  float* __restrict__ sumR,
                                                  float* __restrict__ noo_out) {
    __shared__ float lr[256], ln[256];
    __shared__ int   lc[256];
    __shared__ float wr[4], wn[4];
    __shared__ int   wc[4];
    const float2* __restrict__ P2g = (const float2*)gp;
    const float2* __restrict__ T2g = (const float2*)gt;
    int tid  = threadIdx.x;
    int lane = tid & 63, wave = tid >> 6;
    int cl   = tid & 15;                 // lane within 16-lane group
    int grp  = tid >> 4;                 // block-level group 0..15
    int gb   = lane & ~15;               // group base lane within wave
    int coff = (cl < 15) ? cl : 0;       // chunk within row (lane15 dups 0)

    for (int tt = blockIdx.x; tt < NB; tt += PB2) {
        // pass p handles row (tt*256 + grp + 16*p); chunk stride/pass = 240
        int cb = 15 * (tt * 256 + grp) + coff;      // f32x2 index, < 12.1M
        float2 cp = P2g[cb], ct = T2g[cb];
        for (int pass = 0; pass < 16; ++pass) {
            float2 np = cp, nq = ct;
            if (pass < 15) { np = P2g[cb + 240]; nq = T2g[cb + 240]; }
            cb += 240;
            {
                // ---- box transpose: cols 0..9 live in lanes gb..gb+4 ----
                float2 a0, a1, a2, a3, a4, b0, b1, b2, b4;
                a0.x = __shfl(cp.x, gb + 0); a0.y = __shfl(cp.y, gb + 0);
                a1.x = __shfl(cp.x, gb + 1); a1.y = __shfl(cp.y, gb + 1);
                a2.x = __shfl(cp.x, gb + 2); a2.y = __shfl(cp.y, gb + 2);
                a3.x = __shfl(cp.x, gb + 3); a3.y = __shfl(cp.y, gb + 3);
                a4.x = __shfl(cp.x, gb + 4); a4.y = __shfl(cp.y, gb + 4);
                b0.x = __shfl(ct.x, gb + 0); b0.y = __shfl(ct.y, gb + 0);
                b1.x = __shfl(ct.x, gb + 1); b1.y = __shfl(ct.y, gb + 1);
                b2.x = __shfl(ct.x, gb + 2); b2.y = __shfl(ct.y, gb + 2);
                b4.x = __shfl(ct.x, gb + 4); b4.y = __shfl(ct.y, gb + 4);

                bool coord; float r, noo;
                ROW_PRE
                // ---- class argmax: lanes 5..14 hold cols (2cl,2cl+1) ----
                // lexicographic (value desc, index asc) == first-max scan.
                float v, pcv; int ci;
                if (cl >= 5 && cl <= 14) {
                    int i0 = 2 * cl - 10;
                    if (ct.y > ct.x) { v = ct.y; ci = i0 + 1; pcv = cp.y; }
                    else             { v = ct.x; ci = i0;     pcv = cp.x; }
                } else { v = -__builtin_inff(); ci = 999; pcv = 0.0f; }
#pragma unroll
                for (int k = 1; k < 16; k <<= 1) {
                    float ov = __shfl_xor(v, k);
                    int   oi = __shfl_xor(ci, k);
                    float op = __shfl_xor(pcv, k);
                    bool take = (ov > v) || (ov == v && oi < ci);
                    v  = take ? ov : v;
                    ci = take ? oi : ci;
                    pcv = take ? op : pcv;
                }
                float pc = pcv;
                ROW_POST
                // park row result by row-in-tile index (exact-order replay)
                if (cl == 0) {
                    int rowin = grp + 16 * pass;
                    lr[rowin] = r; ln[rowin] = noo; lc[rowin] = coord ? 1 : 0;
                }
            }
            cp = np; ct = nq;
        }
        __syncthreads();
        // ---- replay R8's exact reduction order: lane == row-in-tile ----
        {
            bool coord = lc[tid] != 0;
            float r = lr[tid], nt = ln[tid];
            float rl = coord ? r : 0.0f;
            unsigned long long bal = __ballot(coord);
            int c = (int)__popcll(bal);
#pragma unroll
            for (int off = 32; off > 0; off >>= 1) {
                rl += __shfl_down(rl, off);
                nt += __shfl_down(nt, off);
            }
            if (lane == 0) { wr[wave] = rl; wn[wave] = nt; wc[wave] = c; }
        }
        __syncthreads();
        if (tid == 0) {
            cnt[tt]     = wc[0] + wc[1] + wc[2] + wc[3];
            sumR[tt]    = wr[0] + wr[1] + wr[2] + wr[3];
            noo_out[tt] = wn[0] + wn[1] + wn[2] + wn[3];
        }
        __syncthreads();   // fences lr/ln/lc + wr/wn/wc reuse for next tile
    }
}

// Diagnostic: known-good pure-stream reader, 64 MB of P, 2048 blocks.
// dur_us => effective read rate; answers "is ~2.7 TB/s a platform wall".
__global__ __launch_bounds__(256) void bw_probe(const f32x4* __restrict__ a,
                                                float* __restrict__ sink) {
    int tid = threadIdx.x;
    long j = (long)blockIdx.x * 256 + tid;
    const long T = 524288;               // 2048 blocks * 256 threads
    f32x4 v0 = a[j],         v1 = a[j + T],     v2 = a[j + 2 * T],
          v3 = a[j + 3 * T], v4 = a[j + 4 * T], v5 = a[j + 5 * T],
          v6 = a[j + 6 * T], v7 = a[j + 7 * T];
    float s = ((v0.x + v0.y) + (v0.z + v0.w)) + ((v1.x + v1.y) + (v1.z + v1.w))
            + ((v2.x + v2.y) + (v2.z + v2.w)) + ((v3.x + v3.y) + (v3.z + v3.w))
            + ((v4.x + v4.y) + (v4.z + v4.w)) + ((v5.x + v5.y) + (v5.z + v5.w))
            + ((v6.x + v6.y) + (v6.z + v6.w)) + ((v7.x + v7.y) + (v7.z + v7.w));
#pragma unroll
    for (int off = 32; off > 0; off >>= 1) s += __shfl_down(s, off);
    if ((tid & 63) == 0) atomicAdd(sink, s);
}

// K2: totals + scan + boundary-block fixup, single block (same as R4).
__global__ __launch_bounds__(256) void yolo_k2(const int* __restrict__ cnt,
                                               const float* __restrict__ sumR,
                                               const float* __restrict__ noo,
                                               const float* __restrict__ gp,
                                               const float* __restrict__ gt,
                                               float* __restrict__ out) {
    __shared__ int   wsum[4];
    __shared__ float wf[4], wn2[4];
    __shared__ int   s_bstar, s_kstar;
    __shared__ float s_base;
    __shared__ int   s_wcnt[4];
    int tid = threadIdx.x;
    int lane = tid & 63, wave = tid >> 6;
    if (tid == 0) { s_bstar = -1; s_kstar = 0; }

    const int PER = 13;                 // 256*13 = 3328 >= 3136
    int start = tid * PER;
    int end = min(NB, start + PER);

    int cloc = 0; float nloc = 0.0f;
    for (int i = start; i < end; ++i) { cloc += cnt[i]; nloc += noo[i]; }

    int incl = cloc;                    // inclusive shfl scan within wave
#pragma unroll
    for (int off = 1; off < 64; off <<= 1) {
        int v = __shfl_up(incl, off);
        if (lane >= off) incl += v;
    }
    if (lane == 63) wsum[wave] = incl;
    __syncthreads();                    // also orders s_bstar init vs walk
    int woff = 0;
#pragma unroll
    for (int w = 0; w < 4; ++w) woff += (w < wave) ? wsum[w] : 0;
    int ex = woff + incl - cloc;        // exclusive global prefix
    int n_obj = wsum[0] + wsum[1] + wsum[2] + wsum[3];
    int n_half = n_obj >> 1;

    float acc = 0.0f;
    int running = ex;
    for (int i = start; i < end; ++i) {
        int ci = cnt[i];
        if (ci > 0) {
            if (running + ci <= n_half) {
                acc += sumR[i];
            } else if (running < n_half) {  // exactly one thread ever
                s_bstar = i;
                s_kstar = n_half - running;
            }
        }
        running += ci;
    }

#pragma unroll
    for (int off = 32; off > 0; off >>= 1) {
        acc  += __shfl_down(acc, off);
        nloc += __shfl_down(nloc, off);
    }
    if (lane == 0) { wf[wave] = acc; wn2[wave] = nloc; }
    __syncthreads();
    if (tid == 0)
        s_base = 5.0f * (wf[0] + wf[1] + wf[2] + wf[3])
               + 0.5f * (wn2[0] + wn2[1] + wn2[2] + wn2[3]);
    __syncthreads();

    // Phase B: boundary block fixup (256 rows)
    int bstar = s_bstar, kstar = s_kstar;
    float total = 0.0f;
    if (bstar >= 0) {                    // uniform branch
        long row = (long)bstar * 256 + tid;
        bool coord; float r, nt;
        row_load_compute(gp, gt, row, coord, r, nt);
        unsigned long long bal = __ballot(coord);
        if (lane == 0) s_wcnt[wave] = (int)__popcll(bal);
        __syncthreads();
        int waveoff = 0;
#pragma unroll
        for (int w = 0; w < 4; ++w) waveoff += (w < wave) ? s_wcnt[w] : 0;
        unsigned long long below_incl =
            (lane == 63) ? bal : (bal & ((1ull << (lane + 1)) - 1ull));
        int rank = waveoff + (int)__popcll(below_incl);  // inclusive rank
        float val = (coord && rank <= kstar) ? r : 0.0f;
#pragma unroll
        for (int off = 32; off > 0; off >>= 1) val += __shfl_down(val, off);
        if (lane == 0) wf[wave] = val;
        __syncthreads();
        if (tid == 0) total = wf[0] + wf[1] + wf[2] + wf[3];
    }
    if (tid == 0) out[0] = s_base + 5.0f * total;
}

extern "C" void kernel_launch(void* const* d_in, const int* in_sizes, int n_in,
                              void* d_out, int out_size, void* d_ws, size_t ws_size,
                              hipStream_t stream) {
    (void)in_sizes; (void)n_in; (void)out_size;
    const float* p = (const float*)d_in[0];   // predictions
    const float* t = (const float*)d_in[1];   // targets
    char* ws = (char*)d_ws;                   // ~38 KB + probe sink
    int*   cnt  = (int*)ws;
    float* sumR = (float*)(ws + (size_t)NB * 4);
    float* noo  = (float*)(ws + (size_t)NB * 8);
    float* out  = (float*)d_out;

    yolo_k1<<<PB2, 256, 0, stream>>>(p, t, cnt, sumR, noo);
    yolo_k2<<<1, 256, 0, stream>>>(cnt, sumR, noo, p, t, out);
    // Diagnostic stream probe (result unused; sink lives past the ws arrays)
    if (ws_size >= (size_t)NB * 12 + 512) {
        float* sink = (float*)(ws + (size_t)NB * 12 + 256);
        bw_probe<<<2048, 256, 0, stream>>>((const f32x4*)p, sink);
    }
}

// Round 4
// 242.121 us; speedup vs baseline: 1.4040x; 1.4040x over previous
//
#include <hip/hip_runtime.h>

// YOLOv1 loss: 802816 rows x 30 f32, two tensors, scalar out.
// R10: R9's probe was invalid — it ended with 8192 device-scope atomicAdds
// to ONE address (13.5 ns each fully serialized = the whole 111 us); its
// shfl-transpose k1 was ~91 us (34 shuffles/row of pure VALU overhead).
// Both reverted. k1/k2 = R8 exactly (best verified, ~72 us, 2.7 TB/s eff).
// New clean probe: 2940 blocks x 256 thr, 8 coalesced f32x4 per thread from
// BOTH tensors (full 192.7 MB, same L3 mix as k1), wave-reduce, plain
// stores to a 64-float sink — no atomics/LDS/barriers. probe_dur =
// dur_us_total - 209.7 even if it misses top-5.
// Decision: probe ~70us => ~2.7 TB/s is the platform wall for this stream,
// k1 is at roofline (remove probe, declare). probe ~31us => rebuild k1 as
// the probe structure with row math folded in.

#define COLS 30
#define NB   3136              // 802816 rows / 256 rows per tile
#define PB   512               // persistent blocks, 2 per CU

typedef float f32x4 __attribute__((ext_vector_type(4)));
typedef float f32x2 __attribute__((ext_vector_type(2)));

// ---------------- per-row math on named scalars (bit-exact) ---------------
#define ROW_MATH_BODY                                                        \
    const float C = 1.0f / 7.0f;                                             \
    float conf = b2.x;                    /* T[4], exactly 0.0 or 1.0 */     \
    coord = (conf == 1.0f);                                                  \
    noo = 0.0f;                                                              \
    if (conf == 0.0f) {                                                      \
        float d4_ = a2.x - conf;                                             \
        float d9_ = a4.y - b4.y;                                             \
        noo = d4_ * d4_ + d9_ * d9_;                                         \
    }                                                                        \
    float T0 = b0.x, T1 = b0.y, T2v = b1.x, T3 = b1.y;                       \
    float tb0 = T0 * T0, tb1 = T1 * T1, tb2 = T2v * T2v, tb3 = T3 * T3;      \
    float tax = tb0 * C - tb2, tay = tb1 * C - tb3;                          \
    float tbx = tax * C + tb2, tby = tay * C + tb3;                          \
    float areaT = (tbx - tax) * (tby - tay);                                 \
    float pax0 = a0.x * C - a1.x, pay0 = a0.y * C - a1.y;                    \
    float pbx0 = pax0 * C + a1.x, pby0 = pay0 * C + a1.y;                    \
    float pax1 = a2.y * C - a3.y, pay1 = a3.x * C - a4.x;                    \
    float pbx1 = pax1 * C + a3.y, pby1 = pay1 * C + a4.x;                    \
    float ltx = fmaxf(pax0, tax), lty = fmaxf(pay0, tay);                    \
    float rbx = fminf(pbx0, tbx), rby = fminf(pby0, tby);                    \
    float wx = fmaxf(rbx - ltx, 0.0f), wy = fmaxf(rby - lty, 0.0f);          \
    float inter = wx * wy;                                                   \
    float areaP = (pbx0 - pax0) * (pby0 - pay0);                             \
    float iou0 = inter / (areaP + areaT - inter);                            \
    ltx = fmaxf(pax1, tax); lty = fmaxf(pay1, tay);                          \
    rbx = fminf(pbx1, tbx); rby = fminf(pby1, tby);                          \
    wx = fmaxf(rbx - ltx, 0.0f); wy = fmaxf(rby - lty, 0.0f);                \
    inter = wx * wy;                                                         \
    areaP = (pbx1 - pax1) * (pby1 - pay1);                                   \
    float iou1 = inter / (areaP + areaT - inter);                            \
    int idx = (iou1 > iou0) ? 1 : 0;      /* argmax, first on ties */        \
    float sx = idx ? a2.y : a0.x;                                            \
    float sy = idx ? a3.x : a0.y;                                            \
    float sw = idx ? a3.y : a1.x;                                            \
    float sh = idx ? a4.x : a1.y;                                            \
    float best = b5.x, pc = a5.x;         /* class argmax, strict > */       \
    CLS_STEP(b5.y,  a5.y)  CLS_STEP(b6.x,  a6.x)  CLS_STEP(b6.y,  a6.y)      \
    CLS_STEP(b7.x,  a7.x)  CLS_STEP(b7.y,  a7.y)  CLS_STEP(b8.x,  a8.x)      \
    CLS_STEP(b8.y,  a8.y)  CLS_STEP(b9.x,  a9.x)  CLS_STEP(b9.y,  a9.y)      \
    CLS_STEP(b10.x, a10.x) CLS_STEP(b10.y, a10.y) CLS_STEP(b11.x, a11.x)     \
    CLS_STEP(b11.y, a11.y) CLS_STEP(b12.x, a12.x) CLS_STEP(b12.y, a12.y)     \
    CLS_STEP(b13.x, a13.x) CLS_STEP(b13.y, a13.y) CLS_STEP(b14.x, a14.x)     \
    CLS_STEP(b14.y, a14.y)                                                   \
    float d0 = sx - T0, d1 = sy - T1, d2 = sw - T2v, d3 = sh - T3;           \
    float dc = pc - 1.0f;                                                    \
    r = d0 * d0 + d1 * d1 + d2 * d2 + d3 * d3 + 2.0f * dc * dc;

#define CLS_STEP(tv, pv) { float v_ = (tv); if (v_ > best) { best = v_; pc = (pv); } }

__device__ __forceinline__ void row_compute_vals(
    float2 a0, float2 a1, float2 a2, float2 a3, float2 a4,
    float2 a5, float2 a6, float2 a7, float2 a8, float2 a9,
    float2 a10, float2 a11, float2 a12, float2 a13, float2 a14,
    float2 b0, float2 b1, float2 b2, float2 b3, float2 b4,
    float2 b5, float2 b6, float2 b7, float2 b8, float2 b9,
    float2 b10, float2 b11, float2 b12, float2 b13, float2 b14,
    bool& coord, float& r, float& noo)
{
    ROW_MATH_BODY
}

// Plain-C++ row load+compute (used only in K2's 256-row fixup).
__device__ __forceinline__ void row_load_compute(
    const float* __restrict__ gp, const float* __restrict__ gt, long row,
    bool& coord, float& r, float& noo)
{
    const float2* P2 = (const float2*)(gp + row * (long)COLS);
    const float2* T2 = (const float2*)(gt + row * (long)COLS);
    float2 a0 = P2[0],  a1 = P2[1],  a2 = P2[2],  a3 = P2[3],  a4 = P2[4];
    float2 a5 = P2[5],  a6 = P2[6],  a7 = P2[7],  a8 = P2[8],  a9 = P2[9];
    float2 a10 = P2[10], a11 = P2[11], a12 = P2[12], a13 = P2[13], a14 = P2[14];
    float2 b0 = T2[0],  b1 = T2[1],  b2 = T2[2],  b3 = T2[3],  b4 = T2[4];
    float2 b5 = T2[5],  b6 = T2[6],  b7 = T2[7],  b8 = T2[8],  b9 = T2[9];
    float2 b10 = T2[10], b11 = T2[11], b12 = T2[12], b13 = T2[13], b14 = T2[14];
    ROW_MATH_BODY
}

// Issue 16 coalesced loads for one 30720B-per-tensor tile, NO wait.
#define STAGE_ISSUE(gpb_, gtb_)                                              \
    asm volatile(                                                            \
        "global_load_dwordx4 %0,  %[o0], %[pb] offset:-4096\n\t"             \
        "global_load_dwordx4 %1,  %[o0], %[pb]\n\t"                          \
        "global_load_dwordx4 %2,  %[o1], %[pb] offset:-4096\n\t"             \
        "global_load_dwordx4 %3,  %[o1], %[pb]\n\t"                          \
        "global_load_dwordx4 %4,  %[o2], %[pb] offset:-4096\n\t"             \
        "global_load_dwordx4 %5,  %[o2], %[pb]\n\t"                          \
        "global_load_dwordx4 %6,  %[o3], %[pb]\n\t"                          \
        "global_load_dwordx2 %7,  %[o4], %[pb]\n\t"                          \
        "global_load_dwordx4 %8,  %[o0], %[tb] offset:-4096\n\t"             \
        "global_load_dwordx4 %9,  %[o0], %[tb]\n\t"                          \
        "global_load_dwordx4 %10, %[o1], %[tb] offset:-4096\n\t"             \
        "global_load_dwordx4 %11, %[o1], %[tb]\n\t"                          \
        "global_load_dwordx4 %12, %[o2], %[tb] offset:-4096\n\t"             \
        "global_load_dwordx4 %13, %[o2], %[tb]\n\t"                          \
        "global_load_dwordx4 %14, %[o3], %[tb]\n\t"                          \
        "global_load_dwordx2 %15, %[o4], %[tb]\n\t"                          \
        : "=&v"(p0), "=&v"(p1), "=&v"(p2), "=&v"(p3), "=&v"(p4), "=&v"(p5),  \
          "=&v"(p6), "=&v"(p7),                                              \
          "=&v"(q0), "=&v"(q1), "=&v"(q2), "=&v"(q3), "=&v"(q4), "=&v"(q5),  \
          "=&v"(q6), "=&v"(q7)                                               \
        : [o0]"v"(o0), [o1]"v"(o1), [o2]"v"(o2), [o3]"v"(o3), [o4]"v"(o4),   \
          [pb]"s"(gpb_), [tb]"s"(gtb_)                                       \
        : "memory")

// Wait for all staging loads; staging regs are "+v" so every ds_write
// consuming them is data-dependent on this asm and cannot be hoisted above.
#define STAGE_WAIT()                                                         \
    asm volatile("s_waitcnt vmcnt(0)"                                        \
        : "+v"(p0), "+v"(p1), "+v"(p2), "+v"(p3), "+v"(p4), "+v"(p5),        \
          "+v"(p6), "+v"(p7),                                                \
          "+v"(q0), "+v"(q1), "+v"(q2), "+v"(q3), "+v"(q4), "+v"(q5),        \
          "+v"(q6), "+v"(q7))

// Linear LDS store (same layout as global) — conflict-free b128/b64 writes.
#define STAGE_TO_LDS()                                                       \
    ldsP[0 * 256 + tid] = p0;  ldsP[1 * 256 + tid] = p1;                     \
    ldsP[2 * 256 + tid] = p2;  ldsP[3 * 256 + tid] = p3;                     \
    ldsP[4 * 256 + tid] = p4;  ldsP[5 * 256 + tid] = p5;                     \
    ldsP[6 * 256 + tid] = p6;                                                \
    ldsT[0 * 256 + tid] = q0;  ldsT[1 * 256 + tid] = q1;                     \
    ldsT[2 * 256 + tid] = q2;  ldsT[3 * 256 + tid] = q3;                     \
    ldsT[4 * 256 + tid] = q4;  ldsT[5 * 256 + tid] = q5;                     \
    ldsT[6 * 256 + tid] = q6;                                                \
    *(f32x2*)(lpf + 7168 + 2 * tid) = p7;                                    \
    *(f32x2*)(ltf + 7168 + 2 * tid) = q7;

// K1: persistent; per 256-row tile emits {coord count, sum coord r, noobj}.
__global__ __launch_bounds__(256, 2) void yolo_k1(const float* __restrict__ gp,
                                                  const float* __restrict__ gt,
                                                  int* __restrict__ cnt,
                                                  float* __restrict__ sumR,
                                                  float* __restrict__ noo) {
    __shared__ f32x4 ldsP[1920];   // 256 rows x 30 f32 = 30720 B, linear
    __shared__ f32x4 ldsT[1920];
    __shared__ float wr[4], wn[4];
    __shared__ int wc[4];
    int tid = threadIdx.x;
    int wave = tid >> 6, lane = tid & 63;
    float* lpf = (float*)ldsP;
    float* ltf = (float*)ldsT;

    unsigned o0 = (unsigned)tid * 16u + 4096u;
    unsigned o1 = (unsigned)tid * 16u + 12288u;
    unsigned o2 = (unsigned)tid * 16u + 20480u;
    unsigned o3 = (unsigned)tid * 16u + 24576u;
    unsigned o4 = (unsigned)tid * 8u  + 28672u;

    f32x4 p0, p1, p2, p3, p4, p5, p6; f32x2 p7;
    f32x4 q0, q1, q2, q3, q4, q5, q6; f32x2 q7;

    int tt = blockIdx.x;
    // Prologue: stage tile tt.
    {
        const float* gpb = gp + (long)tt * (256L * COLS);
        const float* gtb = gt + (long)tt * (256L * COLS);
        STAGE_ISSUE(gpb, gtb);
        STAGE_WAIT();
        STAGE_TO_LDS();
    }
    __syncthreads();

    for (;;) {
        int nt_tile = tt + PB;
        bool have_next = nt_tile < NB;
        if (have_next) {   // uniform branch: issue next tile, keep in flight
            const float* gpb = gp + (long)nt_tile * (256L * COLS);
            const float* gtb = gt + (long)nt_tile * (256L * COLS);
            STAGE_ISSUE(gpb, gtb);
        }

        // Compute tile tt from LDS (stride 30 dwords: 4 dwords/bank per b64
        // wave read = the 128-dword minimum, effectively conflict-free).
        {
            const float2* P2 = (const float2*)(lpf + tid * COLS);
            const float2* T2 = (const float2*)(ltf + tid * COLS);
            float2 a0 = P2[0],  a1 = P2[1],  a2 = P2[2],  a3 = P2[3],  a4 = P2[4];
            float2 a5 = P2[5],  a6 = P2[6],  a7 = P2[7],  a8 = P2[8],  a9 = P2[9];
            float2 a10 = P2[10], a11 = P2[11], a12 = P2[12], a13 = P2[13], a14 = P2[14];
            float2 b0 = T2[0],  b1 = T2[1],  b2 = T2[2],  b3 = T2[3],  b4 = T2[4];
            float2 b5 = T2[5],  b6 = T2[6],  b7 = T2[7],  b8 = T2[8],  b9 = T2[9];
            float2 b10 = T2[10], b11 = T2[11], b12 = T2[12], b13 = T2[13], b14 = T2[14];

            bool coord; float r, nt;
            row_compute_vals(a0, a1, a2, a3, a4, a5, a6, a7, a8, a9,
                             a10, a11, a12, a13, a14,
                             b0, b1, b2, b3, b4, b5, b6, b7, b8, b9,
                             b10, b11, b12, b13, b14, coord, r, nt);
            float rl = coord ? r : 0.0f;

            unsigned long long bal = __ballot(coord);
            int c = (int)__popcll(bal);
#pragma unroll
            for (int off = 32; off > 0; off >>= 1) {
                rl += __shfl_down(rl, off);
                nt += __shfl_down(nt, off);
            }
            if (lane == 0) { wr[wave] = rl; wn[wave] = nt; wc[wave] = c; }
        }
        __syncthreads();   // wr/wn/wc ready AND all lanes done reading tile tt
        if (tid == 0) {
            cnt[tt]  = wc[0] + wc[1] + wc[2] + wc[3];
            sumR[tt] = wr[0] + wr[1] + wr[2] + wr[3];
            noo[tt]  = wn[0] + wn[1] + wn[2] + wn[3];
        }
        if (!have_next) break;
        STAGE_WAIT();
        STAGE_TO_LDS();
        __syncthreads();   // tile nt_tile visible; also fences wr/wn/wc reuse
        tt = nt_tile;
    }
}

// Diagnostic: contention-free pure-stream reader over BOTH tensors
// (192.7 MB, the exact k1 footprint). 2940 blocks x 256 thr, 8 f32x4 per
// thread per tensor, coalesced; wave-reduce; PLAIN stores to a 64-float
// sink (no atomics, no LDS, no barriers). 6,021,120 f32x4 per tensor
// = 2940 * 256 * 8 exactly.
__global__ __launch_bounds__(256) void bw_probe(const f32x4* __restrict__ a,
                                                const f32x4* __restrict__ b,
                                                float* __restrict__ sink) {
    const long T = 2940L * 256;
    long j = (long)blockIdx.x * 256 + threadIdx.x;
    float s = 0.0f;
#pragma unroll
    for (int k = 0; k < 8; ++k) {
        f32x4 v = a[j + (long)k * T];
        f32x4 w = b[j + (long)k * T];
        s += ((v.x + v.y) + (v.z + v.w)) + ((w.x + w.y) + (w.z + w.w));
    }
#pragma unroll
    for (int off = 32; off > 0; off >>= 1) s += __shfl_down(s, off);
    if ((threadIdx.x & 63) == 0)
        sink[(((unsigned)blockIdx.x << 2) + (threadIdx.x >> 6)) & 63u] = s;
}

// K2: totals + scan + boundary-block fixup, single block (same as R4).
__global__ __launch_bounds__(256) void yolo_k2(const int* __restrict__ cnt,
                                               const float* __restrict__ sumR,
                                               const float* __restrict__ noo,
                                               const float* __restrict__ gp,
                                               const float* __restrict__ gt,
                                               float* __restrict__ out) {
    __shared__ int   wsum[4];
    __shared__ float wf[4], wn2[4];
    __shared__ int   s_bstar, s_kstar;
    __shared__ float s_base;
    __shared__ int   s_wcnt[4];
    int tid = threadIdx.x;
    int lane = tid & 63, wave = tid >> 6;
    if (tid == 0) { s_bstar = -1; s_kstar = 0; }

    const int PER = 13;                 // 256*13 = 3328 >= 3136
    int start = tid * PER;
    int end = min(NB, start + PER);

    int cloc = 0; float nloc = 0.0f;
    for (int i = start; i < end; ++i) { cloc += cnt[i]; nloc += noo[i]; }

    int incl = cloc;                    // inclusive shfl scan within wave
#pragma unroll
    for (int off = 1; off < 64; off <<= 1) {
        int v = __shfl_up(incl, off);
        if (lane >= off) incl += v;
    }
    if (lane == 63) wsum[wave] = incl;
    __syncthreads();                    // also orders s_bstar init vs walk
    int woff = 0;
#pragma unroll
    for (int w = 0; w < 4; ++w) woff += (w < wave) ? wsum[w] : 0;
    int ex = woff + incl - cloc;        // exclusive global prefix
    int n_obj = wsum[0] + wsum[1] + wsum[2] + wsum[3];
    int n_half = n_obj >> 1;

    float acc = 0.0f;
    int running = ex;
    for (int i = start; i < end; ++i) {
        int ci = cnt[i];
        if (ci > 0) {
            if (running + ci <= n_half) {
                acc += sumR[i];
            } else if (running < n_half) {  // exactly one thread ever
                s_bstar = i;
                s_kstar = n_half - running;
            }
        }
        running += ci;
    }

#pragma unroll
    for (int off = 32; off > 0; off >>= 1) {
        acc  += __shfl_down(acc, off);
        nloc += __shfl_down(nloc, off);
    }
    if (lane == 0) { wf[wave] = acc; wn2[wave] = nloc; }
    __syncthreads();
    if (tid == 0)
        s_base = 5.0f * (wf[0] + wf[1] + wf[2] + wf[3])
               + 0.5f * (wn2[0] + wn2[1] + wn2[2] + wn2[3]);
    __syncthreads();

    // Phase B: boundary block fixup (256 rows)
    int bstar = s_bstar, kstar = s_kstar;
    float total = 0.0f;
    if (bstar >= 0) {                    // uniform branch
        long row = (long)bstar * 256 + tid;
        bool coord; float r, nt;
        row_load_compute(gp, gt, row, coord, r, nt);
        unsigned long long bal = __ballot(coord);
        if (lane == 0) s_wcnt[wave] = (int)__popcll(bal);
        __syncthreads();
        int waveoff = 0;
#pragma unroll
        for (int w = 0; w < 4; ++w) waveoff += (w < wave) ? s_wcnt[w] : 0;
        unsigned long long below_incl =
            (lane == 63) ? bal : (bal & ((1ull << (lane + 1)) - 1ull));
        int rank = waveoff + (int)__popcll(below_incl);  // inclusive rank
        float val = (coord && rank <= kstar) ? r : 0.0f;
#pragma unroll
        for (int off = 32; off > 0; off >>= 1) val += __shfl_down(val, off);
        if (lane == 0) wf[wave] = val;
        __syncthreads();
        if (tid == 0) total = wf[0] + wf[1] + wf[2] + wf[3];
    }
    if (tid == 0) out[0] = s_base + 5.0f * total;
}

extern "C" void kernel_launch(void* const* d_in, const int* in_sizes, int n_in,
                              void* d_out, int out_size, void* d_ws, size_t ws_size,
                              hipStream_t stream) {
    (void)in_sizes; (void)n_in; (void)out_size;
    const float* p = (const float*)d_in[0];   // predictions
    const float* t = (const float*)d_in[1];   // targets
    char* ws = (char*)d_ws;                   // ~38 KB + probe sink
    int*   cnt  = (int*)ws;
    float* sumR = (float*)(ws + (size_t)NB * 4);
    float* noo  = (float*)(ws + (size_t)NB * 8);
    float* out  = (float*)d_out;

    yolo_k1<<<PB, 256, 0, stream>>>(p, t, cnt, sumR, noo);
    yolo_k2<<<1, 256, 0, stream>>>(cnt, sumR, noo, p, t, out);
    // Diagnostic stream probe (result unused; sink lives past the ws arrays)
    if (ws_size >= (size_t)NB * 12 + 512) {
        float* sink = (float*)(ws + (size_t)NB * 12 + 256);
        bw_probe<<<2940, 256, 0, stream>>>((const f32x4*)p, (const f32x4*)t,
                                           sink);
    }
}

// Round 5
// 219.067 us; speedup vs baseline: 1.5518x; 1.1052x over previous
//
#include <hip/hip_runtime.h>

// YOLOv1 loss: 802816 rows x 30 f32, two tensors, scalar out.
// R11: R10's clean probe read the full 192.7 MB footprint at 5.95 TB/s
// (32.4 us) while every tile-synchronous k1 (R2-R8: gather/coalesced,
// drained/pipelined, 8-18 waves/CU) pinned at 2.6-2.7 TB/s. Conclusion:
// the wall is block-wide synchronization (wait-all vmcnt(0) drains +
// __syncthreads convoys), not request rate / latency / occupancy alone.
// This k1 makes each WAVE an independent probe-like stream:
//   - one wave owns one 256-row tile; 4 sub-chunks of 64 rows through a
//     wave-PRIVATE 15,360B LDS region (coalesced dwordx2, lane l loads
//     chunks l+64m -> linear LDS -> lane l reads row l back). All ordering
//     is within-wave lgkmcnt; ZERO barriers, ZERO cross-wave traffic.
//   - per-sub-chunk ballot+shfl_down reduction is lane-identical to R8's
//     per-wave reduction (R8 wave w held rows 64w+lane); accumulating the
//     4 reduced scalars in s-order replays R8's wr[0]+wr[1]+wr[2]+wr[3]
//     bitwise (all partials are +0-or-positive, so the 0+x seed is exact).
//   - outputs stay 3136-sized; K2 untouched -> final scalar bit-identical.
// LDS 30,720B per 128-thr block -> 5 blocks/CU = 10 free-running waves/CU.

#define COLS 30
#define NB   3136              // 802816 rows / 256 rows per tile

typedef float f32x4 __attribute__((ext_vector_type(4)));
typedef float f32x2 __attribute__((ext_vector_type(2)));

// ---------------- per-row math on named scalars (bit-exact) ---------------
#define ROW_MATH_BODY                                                        \
    const float C = 1.0f / 7.0f;                                             \
    float conf = b2.x;                    /* T[4], exactly 0.0 or 1.0 */     \
    coord = (conf == 1.0f);                                                  \
    noo = 0.0f;                                                              \
    if (conf == 0.0f) {                                                      \
        float d4_ = a2.x - conf;                                             \
        float d9_ = a4.y - b4.y;                                             \
        noo = d4_ * d4_ + d9_ * d9_;                                         \
    }                                                                        \
    float T0 = b0.x, T1 = b0.y, T2v = b1.x, T3 = b1.y;                       \
    float tb0 = T0 * T0, tb1 = T1 * T1, tb2 = T2v * T2v, tb3 = T3 * T3;      \
    float tax = tb0 * C - tb2, tay = tb1 * C - tb3;                          \
    float tbx = tax * C + tb2, tby = tay * C + tb3;                          \
    float areaT = (tbx - tax) * (tby - tay);                                 \
    float pax0 = a0.x * C - a1.x, pay0 = a0.y * C - a1.y;                    \
    float pbx0 = pax0 * C + a1.x, pby0 = pay0 * C + a1.y;                    \
    float pax1 = a2.y * C - a3.y, pay1 = a3.x * C - a4.x;                    \
    float pbx1 = pax1 * C + a3.y, pby1 = pay1 * C + a4.x;                    \
    float ltx = fmaxf(pax0, tax), lty = fmaxf(pay0, tay);                    \
    float rbx = fminf(pbx0, tbx), rby = fminf(pby0, tby);                    \
    float wx = fmaxf(rbx - ltx, 0.0f), wy = fmaxf(rby - lty, 0.0f);          \
    float inter = wx * wy;                                                   \
    float areaP = (pbx0 - pax0) * (pby0 - pay0);                             \
    float iou0 = inter / (areaP + areaT - inter);                            \
    ltx = fmaxf(pax1, tax); lty = fmaxf(pay1, tay);                          \
    rbx = fminf(pbx1, tbx); rby = fminf(pby1, tby);                          \
    wx = fmaxf(rbx - ltx, 0.0f); wy = fmaxf(rby - lty, 0.0f);                \
    inter = wx * wy;                                                         \
    areaP = (pbx1 - pax1) * (pby1 - pay1);                                   \
    float iou1 = inter / (areaP + areaT - inter);                            \
    int idx = (iou1 > iou0) ? 1 : 0;      /* argmax, first on ties */        \
    float sx = idx ? a2.y : a0.x;                                            \
    float sy = idx ? a3.x : a0.y;                                            \
    float sw = idx ? a3.y : a1.x;                                            \
    float sh = idx ? a4.x : a1.y;                                            \
    float best = b5.x, pc = a5.x;         /* class argmax, strict > */       \
    CLS_STEP(b5.y,  a5.y)  CLS_STEP(b6.x,  a6.x)  CLS_STEP(b6.y,  a6.y)      \
    CLS_STEP(b7.x,  a7.x)  CLS_STEP(b7.y,  a7.y)  CLS_STEP(b8.x,  a8.x)      \
    CLS_STEP(b8.y,  a8.y)  CLS_STEP(b9.x,  a9.x)  CLS_STEP(b9.y,  a9.y)      \
    CLS_STEP(b10.x, a10.x) CLS_STEP(b10.y, a10.y) CLS_STEP(b11.x, a11.x)     \
    CLS_STEP(b11.y, a11.y) CLS_STEP(b12.x, a12.x) CLS_STEP(b12.y, a12.y)     \
    CLS_STEP(b13.x, a13.x) CLS_STEP(b13.y, a13.y) CLS_STEP(b14.x, a14.x)     \
    CLS_STEP(b14.y, a14.y)                                                   \
    float d0 = sx - T0, d1 = sy - T1, d2 = sw - T2v, d3 = sh - T3;           \
    float dc = pc - 1.0f;                                                    \
    r = d0 * d0 + d1 * d1 + d2 * d2 + d3 * d3 + 2.0f * dc * dc;

#define CLS_STEP(tv, pv) { float v_ = (tv); if (v_ > best) { best = v_; pc = (pv); } }

__device__ __forceinline__ void row_compute_vals(
    float2 a0, float2 a1, float2 a2, float2 a3, float2 a4,
    float2 a5, float2 a6, float2 a7, float2 a8, float2 a9,
    float2 a10, float2 a11, float2 a12, float2 a13, float2 a14,
    float2 b0, float2 b1, float2 b2, float2 b3, float2 b4,
    float2 b5, float2 b6, float2 b7, float2 b8, float2 b9,
    float2 b10, float2 b11, float2 b12, float2 b13, float2 b14,
    bool& coord, float& r, float& noo)
{
    ROW_MATH_BODY
}

// Plain-C++ row load+compute (used only in K2's 256-row fixup).
__device__ __forceinline__ void row_load_compute(
    const float* __restrict__ gp, const float* __restrict__ gt, long row,
    bool& coord, float& r, float& noo)
{
    const float2* P2 = (const float2*)(gp + row * (long)COLS);
    const float2* T2 = (const float2*)(gt + row * (long)COLS);
    float2 a0 = P2[0],  a1 = P2[1],  a2 = P2[2],  a3 = P2[3],  a4 = P2[4];
    float2 a5 = P2[5],  a6 = P2[6],  a7 = P2[7],  a8 = P2[8],  a9 = P2[9];
    float2 a10 = P2[10], a11 = P2[11], a12 = P2[12], a13 = P2[13], a14 = P2[14];
    float2 b0 = T2[0],  b1 = T2[1],  b2 = T2[2],  b3 = T2[3],  b4 = T2[4];
    float2 b5 = T2[5],  b6 = T2[6],  b7 = T2[7],  b8 = T2[8],  b9 = T2[9];
    float2 b10 = T2[10], b11 = T2[11], b12 = T2[12], b13 = T2[13], b14 = T2[14];
    ROW_MATH_BODY
}

// K1: one WAVE per 256-row tile; 4 sub-chunks of 64 rows via wave-private
// LDS; no barriers, no cross-wave communication. 128-thr blocks (2 waves),
// 30,720B LDS -> 5 blocks/CU = 10 independent wave-streams per CU.
__global__ __launch_bounds__(128, 3) void yolo_k1(const float* __restrict__ gp,
                                                  const float* __restrict__ gt,
                                                  int* __restrict__ cnt,
                                                  float* __restrict__ sumR,
                                                  float* __restrict__ noo_out) {
    __shared__ float2 lds2[2][1920];    // per wave: 960 P + 960 T f32x2
    int tid  = threadIdx.x;
    int lane = tid & 63;
    int wib  = tid >> 6;                 // wave in block (0,1)
    int t    = blockIdx.x * 2 + wib;     // tile owned by this wave
    if (t >= NB) return;

    float2* L = lds2[wib];
    const float2* P2g = (const float2*)gp;
    const float2* T2g = (const float2*)gt;

    float sumA = 0.0f, nooA = 0.0f;
    int   cntA = 0;

    for (int s = 0; s < 4; ++s) {
        // ---- coalesced stage: 64 rows = 960 f32x2 per tensor ----
        int base = 3840 * t + 960 * s + lane;      // f32x2 index
        float2 vp[15], vt[15];
#pragma unroll
        for (int m = 0; m < 15; ++m) vp[m] = P2g[base + 64 * m];
#pragma unroll
        for (int m = 0; m < 15; ++m) vt[m] = T2g[base + 64 * m];
#pragma unroll
        for (int m = 0; m < 15; ++m) L[m * 64 + lane] = vp[m];
#pragma unroll
        for (int m = 0; m < 15; ++m) L[960 + m * 64 + lane] = vt[m];
        // within-wave LDS ordering: compiler inserts lgkmcnt before reads.

        // ---- row read: lane = row-in-sub-chunk ----
        const float2* Pr = &L[lane * 15];
        const float2* Tr = &L[960 + lane * 15];
        float2 a0 = Pr[0],  a1 = Pr[1],  a2 = Pr[2],  a3 = Pr[3],  a4 = Pr[4];
        float2 a5 = Pr[5],  a6 = Pr[6],  a7 = Pr[7],  a8 = Pr[8],  a9 = Pr[9];
        float2 a10 = Pr[10], a11 = Pr[11], a12 = Pr[12], a13 = Pr[13], a14 = Pr[14];
        float2 b0 = Tr[0],  b1 = Tr[1],  b2 = Tr[2],  b3 = Tr[3],  b4 = Tr[4];
        float2 b5 = Tr[5],  b6 = Tr[6],  b7 = Tr[7],  b8 = Tr[8],  b9 = Tr[9];
        float2 b10 = Tr[10], b11 = Tr[11], b12 = Tr[12], b13 = Tr[13], b14 = Tr[14];

        bool coord; float r, nt;
        row_compute_vals(a0, a1, a2, a3, a4, a5, a6, a7, a8, a9,
                         a10, a11, a12, a13, a14,
                         b0, b1, b2, b3, b4, b5, b6, b7, b8, b9,
                         b10, b11, b12, b13, b14, coord, r, nt);
        float rl = coord ? r : 0.0f;

        // ---- per-sub-chunk reduction: identical tree to R8's wave s ----
        unsigned long long bal = __ballot(coord);
        int c = (int)__popcll(bal);
#pragma unroll
        for (int off = 32; off > 0; off >>= 1) {
            rl += __shfl_down(rl, off);
            nt += __shfl_down(nt, off);
        }
        cntA += c;          // uniform across lanes
        sumA += rl;         // lane0 carries the true partial
        nooA += nt;
    }
    if (lane == 0) {
        cnt[t]     = cntA;
        sumR[t]    = sumA;   // == ((wr0+wr1)+wr2)+wr3 bitwise (R8 order)
        noo_out[t] = nooA;
    }
}

// K2: totals + scan + boundary-block fixup, single block (same as R4).
__global__ __launch_bounds__(256) void yolo_k2(const int* __restrict__ cnt,
                                               const float* __restrict__ sumR,
                                               const float* __restrict__ noo,
                                               const float* __restrict__ gp,
                                               const float* __restrict__ gt,
                                               float* __restrict__ out) {
    __shared__ int   wsum[4];
    __shared__ float wf[4], wn2[4];
    __shared__ int   s_bstar, s_kstar;
    __shared__ float s_base;
    __shared__ int   s_wcnt[4];
    int tid = threadIdx.x;
    int lane = tid & 63, wave = tid >> 6;
    if (tid == 0) { s_bstar = -1; s_kstar = 0; }

    const int PER = 13;                 // 256*13 = 3328 >= 3136
    int start = tid * PER;
    int end = min(NB, start + PER);

    int cloc = 0; float nloc = 0.0f;
    for (int i = start; i < end; ++i) { cloc += cnt[i]; nloc += noo[i]; }

    int incl = cloc;                    // inclusive shfl scan within wave
#pragma unroll
    for (int off = 1; off < 64; off <<= 1) {
        int v = __shfl_up(incl, off);
        if (lane >= off) incl += v;
    }
    if (lane == 63) wsum[wave] = incl;
    __syncthreads();                    // also orders s_bstar init vs walk
    int woff = 0;
#pragma unroll
    for (int w = 0; w < 4; ++w) woff += (w < wave) ? wsum[w] : 0;
    int ex = woff + incl - cloc;        // exclusive global prefix
    int n_obj = wsum[0] + wsum[1] + wsum[2] + wsum[3];
    int n_half = n_obj >> 1;

    float acc = 0.0f;
    int running = ex;
    for (int i = start; i < end; ++i) {
        int ci = cnt[i];
        if (ci > 0) {
            if (running + ci <= n_half) {
                acc += sumR[i];
            } else if (running < n_half) {  // exactly one thread ever
                s_bstar = i;
                s_kstar = n_half - running;
            }
        }
        running += ci;
    }

#pragma unroll
    for (int off = 32; off > 0; off >>= 1) {
        acc  += __shfl_down(acc, off);
        nloc += __shfl_down(nloc, off);
    }
    if (lane == 0) { wf[wave] = acc; wn2[wave] = nloc; }
    __syncthreads();
    if (tid == 0)
        s_base = 5.0f * (wf[0] + wf[1] + wf[2] + wf[3])
               + 0.5f * (wn2[0] + wn2[1] + wn2[2] + wn2[3]);
    __syncthreads();

    // Phase B: boundary block fixup (256 rows)
    int bstar = s_bstar, kstar = s_kstar;
    float total = 0.0f;
    if (bstar >= 0) {                    // uniform branch
        long row = (long)bstar * 256 + tid;
        bool coord; float r, nt;
        row_load_compute(gp, gt, row, coord, r, nt);
        unsigned long long bal = __ballot(coord);
        if (lane == 0) s_wcnt[wave] = (int)__popcll(bal);
        __syncthreads();
        int waveoff = 0;
#pragma unroll
        for (int w = 0; w < 4; ++w) waveoff += (w < wave) ? s_wcnt[w] : 0;
        unsigned long long below_incl =
            (lane == 63) ? bal : (bal & ((1ull << (lane + 1)) - 1ull));
        int rank = waveoff + (int)__popcll(below_incl);  // inclusive rank
        float val = (coord && rank <= kstar) ? r : 0.0f;
#pragma unroll
        for (int off = 32; off > 0; off >>= 1) val += __shfl_down(val, off);
        if (lane == 0) wf[wave] = val;
        __syncthreads();
        if (tid == 0) total = wf[0] + wf[1] + wf[2] + wf[3];
    }
    if (tid == 0) out[0] = s_base + 5.0f * total;
}

extern "C" void kernel_launch(void* const* d_in, const int* in_sizes, int n_in,
                              void* d_out, int out_size, void* d_ws, size_t ws_size,
                              hipStream_t stream) {
    (void)in_sizes; (void)n_in; (void)out_size; (void)ws_size;
    const float* p = (const float*)d_in[0];   // predictions
    const float* t = (const float*)d_in[1];   // targets
    char* ws = (char*)d_ws;                   // ~38 KB used
    int*   cnt  = (int*)ws;
    float* sumR = (float*)(ws + (size_t)NB * 4);
    float* noo  = (float*)(ws + (size_t)NB * 8);
    float* out  = (float*)d_out;

    yolo_k1<<<NB / 2, 128, 0, stream>>>(p, t, cnt, sumR, noo);
    yolo_k2<<<1, 256, 0, stream>>>(cnt, sumR, noo, p, t, out);
}